// Round 12
// baseline (200.686 us; speedup 1.0000x reference)
//
#include <hip/hip_runtime.h>

// CausalSelfAttention: B=2, T=2048, C=1024, H=16, HD=64.
// Inputs/outputs f32; internal bf16 MFMA.
//
// Pipeline (5 launches):
//   1. prep: fused {cast x -> xb bf16} + {transpose+cast w_attn} +
//      {transpose+cast w_proj} in one flat-grid kernel.
//   2. gemm_bt<QKV>: xb @ wattnT^T + b_attn -> Q,K bf16 [B,H,T,64]
//      (K pre-scaled by 0.125*log2e) and V DIRECTLY into fragment-
//      permuted Vt [bh][d][t]. Q/K blocks compute C^T via MFMA operand
//      swap -> u16x4 stores. XCD-swizzled block ids.
//      Main loop: double-buffered with COUNTED vmcnt across RAW
//      s_barriers (T4): issue next tile's 4 global_load_lds, then
//      s_waitcnt vmcnt(4) (drains only the PREVIOUS tile's loads) +
//      s_barrier. This tile's loads stay in flight through the whole
//      ds_read+MFMA phase — unlike __syncthreads, whose implicit
//      vmcnt(0) drain was the round-6 regression.
//   3. attn_split: flash attention, S^T formulation, no-max softmax,
//      SPLIT-KV with balanced slice ranges; double-buffered XOR-swizzled
//      LDS tiles; one barrier per kv tile; raw v_exp_f32; setprio(1)
//      around MFMA cluster; (256,5) -> 5 blocks/CU.
//   4. attn_combine: sum <=4 partials, divide, write Y bf16
//   5. gemm_bt<PLAIN>: Y @ wprojT^T + b_proj -> out f32

typedef unsigned short u16;
typedef unsigned short u16x8 __attribute__((ext_vector_type(8)));
typedef unsigned short u16x4 __attribute__((ext_vector_type(4)));
typedef __bf16 bf16x8 __attribute__((ext_vector_type(8)));
typedef __bf16 bf16x4 __attribute__((ext_vector_type(4)));
typedef float f32x4 __attribute__((ext_vector_type(4)));

#define MFMA16(a, b, c) __builtin_amdgcn_mfma_f32_16x16x32_bf16(a, b, c, 0, 0, 0)

static __device__ __forceinline__ u16 f2b(float f) {
  union { float f; unsigned int i; } x; x.f = f;
  unsigned int r = x.i + 0x7fffu + ((x.i >> 16) & 1u);  // RNE
  return (u16)(r >> 16);
}
static __device__ __forceinline__ float b2f(u16 u) {
  union { unsigned int i; float f; } x; x.i = ((unsigned int)u) << 16; return x.f;
}

// async global->LDS, 16B per lane. LDS dest resolves to wave-uniform base
// (lane0's pointer) + lane*16 — our addressing is lane-linear so this matches.
static __device__ __forceinline__ void gload_lds16(const u16* g, u16* l) {
#if defined(__HIP_DEVICE_COMPILE__)
  __builtin_amdgcn_global_load_lds(
      (const __attribute__((address_space(1))) unsigned int*)g,
      (__attribute__((address_space(3))) unsigned int*)l,
      16, 0, 0);
#else
  (void)g; (void)l;
#endif
}

// ---------------------------------------------------------------- prep
// Fused: [0,2048) cast x f32->bf16 (8/thread); [2048,5120) transpose
// w_attn [1024][3072] -> wattnT [3072][1024]; [5120,6144) transpose
// w_proj [1024][1024] -> wprojT. Branch is block-uniform.
__global__ __launch_bounds__(256) void prep(
    const float* __restrict__ x, const float* __restrict__ w_attn,
    const float* __restrict__ w_proj, u16* __restrict__ xb,
    u16* __restrict__ wattnT, u16* __restrict__ wprojT) {
  __shared__ u16 tile[32][33];
  const int bid = blockIdx.x;
  const int tid = threadIdx.x;

  if (bid < 2048) {
    int i = (bid * 256 + tid) * 8;
    float4 a = *(const float4*)&x[i];
    float4 b = *(const float4*)&x[i + 4];
    u16x8 o;
    o[0] = f2b(a.x); o[1] = f2b(a.y); o[2] = f2b(a.z); o[3] = f2b(a.w);
    o[4] = f2b(b.x); o[5] = f2b(b.y); o[6] = f2b(b.z); o[7] = f2b(b.w);
    *(u16x8*)&xb[i] = o;
    return;
  }

  const float* in;
  u16* out;
  int bx, by, R, Cc;
  if (bid < 5120) {
    int b = bid - 2048;
    bx = b % 96; by = b / 96; R = 1024; Cc = 3072;
    in = w_attn; out = wattnT;
  } else {
    int b = bid - 5120;
    bx = b % 32; by = b / 32; R = 1024; Cc = 1024;
    in = w_proj; out = wprojT;
  }
  const int tx = tid & 31, ty = tid >> 5;  // 32 x 8
#pragma unroll
  for (int i = 0; i < 4; i++) {
    int r = by * 32 + ty + i * 8;
    int c = bx * 32 + tx;
    tile[ty + i * 8][tx] = f2b(in[r * Cc + c]);
  }
  __syncthreads();
#pragma unroll
  for (int i = 0; i < 4; i++) {
    int r = bx * 32 + ty + i * 8;
    int c = by * 32 + tx;
    out[r * R + c] = tile[tx][ty + i * 8];
  }
}

// ---------------------------------------------------------------- GEMM
// MODE 0: QKV (bf16 scatter outputs). MODE 1: plain f32 out.
// BK=32, double-buffered (32KB LDS), counted-vmcnt pipeline:
//   iter i: issue 4 loads -> buf[cur^1]; vmcnt(4) (drains iter i-1's 4
//   loads -> buf[cur], NOT this iter's); s_barrier; ds_read+MFMA on
//   buf[cur]; lgkmcnt(0); s_barrier (protects buf[cur] from iter i+1's
//   stage). Loads ride through the compute phase.
template <int MODE>
__global__ __launch_bounds__(256, 3) void gemm_bt(
    const u16* __restrict__ A, const u16* __restrict__ Bt,
    const float* __restrict__ bias, float* __restrict__ out,
    u16* __restrict__ Qb, u16* __restrict__ Kb, u16* __restrict__ Vtb,
    int M, int N, int K) {
  __shared__ u16 lA[2][128 * 32];
  __shared__ u16 lB[2][128 * 32];

  const int tid = threadIdx.x;
  const int lane = tid & 63;
  const int w = tid >> 6;
  const int wm = (w >> 1) * 64, wn = (w & 1) * 64;
  const int l15 = lane & 15, quad = lane >> 4;

  // XCD-aware swizzle: contiguous chunk of remapped ids per XCD.
  // nwg % 8 == 0 for both launches (768, 256) -> bijective.
  const int nx = gridDim.x;
  const int id = blockIdx.y * nx + blockIdx.x;
  const int chunk = (nx * gridDim.y) >> 3;
  const int nid = (id & 7) * chunk + (id >> 3);
  const int m0 = (nid / nx) * 128, n0 = (nid % nx) * 128;

  const bool swapcd = (MODE == 0) && (n0 < 2048);  // Q/K blocks: C^T

  const int srow = lane >> 2;
  const int scol = (lane & 3) * 8;

  f32x4 acc[4][4] = {};

  auto stage = [&](int buf, int k0) {
#pragma unroll
    for (int h = 0; h < 2; h++) {
      int r = h * 64 + w * 16 + srow;
      gload_lds16(&A[(m0 + r) * K + k0 + scol], &lA[buf][h * 2048 + w * 512 + lane * 8]);
      gload_lds16(&Bt[(n0 + r) * K + k0 + scol], &lB[buf][h * 2048 + w * 512 + lane * 8]);
    }
  };

  // prologue: fill buffer 0, full drain
  stage(0, 0);
  asm volatile("s_waitcnt vmcnt(0)" ::: "memory");
  __builtin_amdgcn_s_barrier();
  __builtin_amdgcn_sched_barrier(0);

  int cur = 0;
  for (int k0 = 0; k0 < K; k0 += 32) {
    if (k0 + 32 < K) {
      stage(cur ^ 1, k0 + 32);     // 4 loads -> buf[cur^1], stay in flight
      asm volatile("s_waitcnt vmcnt(4)" ::: "memory");  // drain prev 4 only
    } else {
      asm volatile("s_waitcnt vmcnt(0)" ::: "memory");  // last iter: drain all
    }
    __builtin_amdgcn_sched_barrier(0);
    __builtin_amdgcn_s_barrier();   // buf[cur] now fully populated, all waves
    __builtin_amdgcn_sched_barrier(0);

    bf16x8 af[4], bfr[4];
#pragma unroll
    for (int mi = 0; mi < 4; mi++)
      af[mi] = *(const bf16x8*)&lA[cur][(wm + mi * 16 + l15) * 32 + quad * 8];
#pragma unroll
    for (int ni = 0; ni < 4; ni++)
      bfr[ni] = *(const bf16x8*)&lB[cur][(wn + ni * 16 + l15) * 32 + quad * 8];
    if (swapcd) {
#pragma unroll
      for (int mi = 0; mi < 4; mi++)
#pragma unroll
        for (int ni = 0; ni < 4; ni++)
          acc[mi][ni] = MFMA16(bfr[ni], af[mi], acc[mi][ni]);
    } else {
#pragma unroll
      for (int mi = 0; mi < 4; mi++)
#pragma unroll
        for (int ni = 0; ni < 4; ni++)
          acc[mi][ni] = MFMA16(af[mi], bfr[ni], acc[mi][ni]);
    }

    asm volatile("s_waitcnt lgkmcnt(0)" ::: "memory");  // all ds_reads retired
    __builtin_amdgcn_sched_barrier(0);
    __builtin_amdgcn_s_barrier();   // buf[cur] free for next iter's stage
    cur ^= 1;
  }

  if (MODE == 1) {
    // plain f32 out: acc[mi][ni][reg] is C[m][n], m=..+quad*4+reg, n=..+l15
#pragma unroll
    for (int mi = 0; mi < 4; mi++) {
#pragma unroll
      for (int ni = 0; ni < 4; ni++) {
        int n = n0 + wn + ni * 16 + l15;
        float bv = bias[n];
#pragma unroll
        for (int reg = 0; reg < 4; reg++) {
          int m = m0 + wm + mi * 16 + quad * 4 + reg;
          out[m * N + n] = acc[mi][ni][reg] + bv;
        }
      }
    }
  } else if (n0 < 2048) {
    // Q/K (swapped): lane holds n = n0+wn+ni*16+quad*4+reg, m = ..+l15.
    const int which = n0 >> 10;          // 0=q 1=k (uniform per block)
    u16* dst = which ? Kb : Qb;
    const float scale = which ? 0.18033688011112042f : 1.0f;  // 0.125*log2e
    const int b = m0 >> 11;
    const int hh = ((n0 & 1023) + wn) >> 6;
    const int tbase = (m0 & 2047) + wm + l15;
#pragma unroll
    for (int mi = 0; mi < 4; mi++) {
      u16* drow = dst + (((b << 4) + hh) * 2048 + tbase + mi * 16) * 64;
#pragma unroll
      for (int ni = 0; ni < 4; ni++) {
        int d0 = ni * 16 + quad * 4;
        float4 bv4 = *(const float4*)&bias[n0 + wn + d0];
        u16x4 o;
        o[0] = f2b((acc[mi][ni][0] + bv4.x) * scale);
        o[1] = f2b((acc[mi][ni][1] + bv4.y) * scale);
        o[2] = f2b((acc[mi][ni][2] + bv4.z) * scale);
        o[3] = f2b((acc[mi][ni][3] + bv4.w) * scale);
        *(u16x4*)&drow[d0] = o;
      }
    }
  } else {
    // V (unswapped): lane holds m = ..+quad*4+reg (4 consecutive t), fixed
    // d = ni*16+l15. Fragment permutation: tp = quad*8 + (mi&1)*4 + reg,
    // contiguous in reg -> u16x4 store into Vt[bh][d][t32 + tp].
    const int b = m0 >> 11;
    const int hh = ((n0 & 1023) + wn) >> 6;
    const int bh = (b << 4) + hh;
#pragma unroll
    for (int mi = 0; mi < 4; mi++) {
      int t32 = (m0 & 2047) + wm + (mi >> 1) * 32;
      int tp0 = quad * 8 + (mi & 1) * 4;
#pragma unroll
      for (int ni = 0; ni < 4; ni++) {
        int d = ni * 16 + l15;
        float bv = bias[n0 + wn + d];
        u16x4 o;
        o[0] = f2b(acc[mi][ni][0] + bv);
        o[1] = f2b(acc[mi][ni][1] + bv);
        o[2] = f2b(acc[mi][ni][2] + bv);
        o[3] = f2b(acc[mi][ni][3] + bv);
        *(u16x4*)&Vtb[(bh * 64 + d) * 2048 + t32 + tp0] = o;
      }
    }
  }
}

// ---------------------------------------------------------------- attention
// Split-kv flash attention. Block = (x -> (qt, slice), bh). 4 waves x 16
// q-rows. Slice s of ns covers kv tiles [s*(qt+1)/ns, (s+1)*(qt+1)/ns).
// S^T formulation; l via ones-B MFMA. Double-buffered LDS, one barrier
// per tile. LDS tiles XOR-swizzled: row stride 64 u16 (128B), 16B chunk
// ^= (row&7) -> conflict-free b128 reads. setprio(1) around MFMA cluster.
__global__ __launch_bounds__(256, 5) void attn_split(
    const u16* __restrict__ Qg, const u16* __restrict__ Kg,
    const u16* __restrict__ Vt, u16* __restrict__ Yg,
    u16* __restrict__ Opart, float* __restrict__ lpart) {
  __shared__ u16 lk[2][64 * 64];     // K tile  [kv][d]  (swizzled)
  __shared__ u16 lvt[2][64 * 64];    // Vt tile [d][kv]  (swizzled, frag order)

  const int x = blockIdx.x;
  const int bh = blockIdx.y;
  int qt, s, ns;
  if (x < 8)       { qt = x;                s = 0;            ns = 1; }
  else if (x < 24) { int r = x - 8;  qt = 8  + (r >> 1); s = r & 1; ns = 2; }
  else if (x < 48) { int r = x - 24; qt = 16 + r / 3;    s = r % 3; ns = 3; }
  else             { int r = x - 48; qt = 24 + (r >> 2); s = r & 3; ns = 4; }
  const int total = qt + 1;
  const int kts  = (s * total) / ns;
  const int kend = ((s + 1) * total) / ns;

  const int tid = threadIdx.x;
  const int lane = tid & 63;
  const int w = tid >> 6;
  const int l15 = lane & 15, quad = lane >> 4;
  const int qbase = qt * 64;
  const int base = bh * 2048 * 64;
  const int vbase = bh * 64 * 2048;
  const int qloc = w * 16 + l15;
  const int xsw = (l15 & 7) << 3;    // read-side swizzle (row&7 == l15&7)

  const int sr = tid >> 3;           // 0..31
  const int sc = (tid & 7) * 8;      // 0..56

  // Q B-fragments
  const u16* qrow = Qg + base + (qbase + w * 16 + l15) * 64;
  bf16x8 bq0 = *(const bf16x8*)&qrow[quad * 8];
  bf16x8 bq1 = *(const bf16x8*)&qrow[32 + quad * 8];

  u16x8 onesu = {0x3F80, 0x3F80, 0x3F80, 0x3F80, 0x3F80, 0x3F80, 0x3F80, 0x3F80};
  bf16x8 ones = *(const bf16x8*)&onesu;

  const u16* kp = Kg + base;
  const u16* vp = Vt + vbase;

  // preload first tile of the slice
  u16x8 kr[2], vr[2];
  {
    int kvb = kts * 64;
#pragma unroll
    for (int h = 0; h < 2; h++) {
      int r = sr + h * 32;
      kr[h] = *(const u16x8*)&kp[(kvb + r) * 64 + sc];
      vr[h] = *(const u16x8*)&vp[r * 2048 + kvb + sc];
    }
  }

  f32x4 oacc[4] = {};
  f32x4 lacc = {};

  int cur = 0;
  for (int kt = kts; kt < kend; kt++) {
    u16* lkc = lk[cur];
    u16* lvc = lvt[cur];
#pragma unroll
    for (int h = 0; h < 2; h++) {
      int r = sr + h * 32;
      int cs = sc ^ ((r & 7) << 3);          // swizzled 16B chunk
      *(u16x8*)&lkc[r * 64 + cs] = kr[h];
      *(u16x8*)&lvc[r * 64 + cs] = vr[h];
    }
    __syncthreads();
    if (kt + 1 < kend) {
      int kvb = (kt + 1) * 64;
#pragma unroll
      for (int h = 0; h < 2; h++) {
        int r = sr + h * 32;
        kr[h] = *(const u16x8*)&kp[(kvb + r) * 64 + sc];
        vr[h] = *(const u16x8*)&vp[r * 2048 + kvb + sc];
      }
    }

    const bool diag = (kt == qt);

#pragma unroll
    for (int u = 0; u < 2; u++) {
      bf16x8 pa;
      __builtin_amdgcn_s_setprio(1);
#pragma unroll
      for (int half = 0; half < 2; half++) {
        int nt = 2 * u + half;
        const u16* kb = &lkc[(nt * 16 + l15) * 64];
        bf16x8 ak0 = *(const bf16x8*)&kb[(quad * 8) ^ xsw];
        bf16x8 ak1 = *(const bf16x8*)&kb[(32 + quad * 8) ^ xsw];
        f32x4 st = {};
        st = MFMA16(ak0, bq0, st);
        st = MFMA16(ak1, bq1, st);
#pragma unroll
        for (int reg = 0; reg < 4; reg++) {
          float sv = st[reg];
          if (diag && (nt * 16 + quad * 4 + reg) > qloc) sv = -1e30f;
          pa[half * 4 + reg] = (__bf16)__builtin_amdgcn_exp2f(sv);
        }
      }
      // row-sum on the MFMA pipe: lacc[reg] = l[q = w*16 + quad*4 + reg]
      lacc = MFMA16(pa, ones, lacc);
#pragma unroll
      for (int dt = 0; dt < 4; dt++) {
        bf16x8 bv = *(const bf16x8*)&lvc[(dt * 16 + l15) * 64 +
                                         ((u * 32 + quad * 8) ^ xsw)];
        oacc[dt] = MFMA16(pa, bv, oacc[dt]);
      }
      __builtin_amdgcn_s_setprio(0);
    }
    cur ^= 1;
  }

  if (ns == 1) {
    const int b = bh >> 4, hh = bh & 15;
    float inv[4];
#pragma unroll
    for (int reg = 0; reg < 4; reg++) inv[reg] = 1.0f / lacc[reg];
#pragma unroll
    for (int dt = 0; dt < 4; dt++)
#pragma unroll
      for (int reg = 0; reg < 4; reg++) {
        int q = qbase + w * 16 + quad * 4 + reg;
        int col = hh * 64 + dt * 16 + l15;
        Yg[(b * 2048 + q) * 1024 + col] = f2b(oacc[dt][reg] * inv[reg]);
      }
  } else {
    const int p = bh * 80 + x;
    u16* op = Opart + p * 4096 + (w * 16) * 64;  // rows w*16..w*16+15
#pragma unroll
    for (int dt = 0; dt < 4; dt++)
#pragma unroll
      for (int reg = 0; reg < 4; reg++)
        op[(quad * 4 + reg) * 64 + dt * 16 + l15] = f2b(oacc[dt][reg]);
    if (l15 == 0) {
#pragma unroll
      for (int reg = 0; reg < 4; reg++)
        lpart[p * 64 + w * 16 + quad * 4 + reg] = lacc[reg];
    }
  }
}

// combine <=4 partials for qt >= 8
__global__ __launch_bounds__(256) void attn_combine(
    const u16* __restrict__ Opart, const float* __restrict__ lpart,
    u16* __restrict__ Yg) {
  const int qt = 8 + blockIdx.x;    // 8..31
  const int bh = blockIdx.y;
  const int tid = threadIdx.x;
  const int row = tid >> 2;         // 0..63
  const int cg = (tid & 3) * 16;    // 0,16,32,48
  int xb, ns;
  if (qt < 16)      { xb = 8  + (qt - 8) * 2;  ns = 2; }
  else if (qt < 24) { xb = 24 + (qt - 16) * 3; ns = 3; }
  else              { xb = 48 + (qt - 24) * 4; ns = 4; }

  float acc[16] = {};
  float lsum = 0.f;
  for (int i = 0; i < ns; i++) {
    int p = bh * 80 + xb + i;
    lsum += lpart[p * 64 + row];
    const u16* oprow = Opart + p * 4096 + row * 64 + cg;
    u16x8 a = *(const u16x8*)&oprow[0];
    u16x8 b = *(const u16x8*)&oprow[8];
#pragma unroll
    for (int j = 0; j < 8; j++) { acc[j] += b2f(a[j]); acc[8 + j] += b2f(b[j]); }
  }
  float inv = 1.0f / lsum;
  u16x8 o0, o1;
#pragma unroll
  for (int j = 0; j < 8; j++) { o0[j] = f2b(acc[j] * inv); o1[j] = f2b(acc[8 + j] * inv); }
  const int b = bh >> 4, hh = bh & 15;
  u16* y = Yg + ((long)(b * 2048 + qt * 64 + row)) * 1024 + hh * 64 + cg;
  *(u16x8*)&y[0] = o0;
  *(u16x8*)&y[8] = o1;
}

// ---------------------------------------------------------------- launch
extern "C" void kernel_launch(void* const* d_in, const int* in_sizes, int n_in,
                              void* d_out, int out_size, void* d_ws, size_t ws_size,
                              hipStream_t stream) {
  const float* x      = (const float*)d_in[0];
  const float* w_attn = (const float*)d_in[1];
  const float* b_attn = (const float*)d_in[2];
  const float* w_proj = (const float*)d_in[3];
  const float* b_proj = (const float*)d_in[4];
  float* out = (float*)d_out;

  char* ws = (char*)d_ws;
  u16* wattnT = (u16*)(ws);                  //  6291456 B
  u16* wprojT = (u16*)(ws + 6291456);        //  2097152 B
  u16* xb     = (u16*)(ws + 8388608);        //  8388608 B
  u16* Qb     = (u16*)(ws + 16777216);
  u16* Kb     = (u16*)(ws + 25165824);
  u16* Vt     = (u16*)(ws + 33554432);       //  written directly by QKV gemm
  u16* Yb     = (u16*)(ws + 41943040);       //  8388608 B -> 50331648
  u16* Opart  = (u16*)(ws + 50331648);       //  20971520 B
  float* lpart = (float*)(ws + 71303168);    //  655360 B -> 71958528 total

  prep<<<6144, 256, 0, stream>>>(x, w_attn, w_proj, xb, wattnT, wprojT);
  gemm_bt<0><<<dim3(24, 32), 256, 0, stream>>>(xb, wattnT, b_attn, nullptr,
                                               Qb, Kb, Vt, 4096, 3072, 1024);
  attn_split<<<dim3(80, 32), 256, 0, stream>>>(Qb, Kb, Vt, Yb, Opart, lpart);
  attn_combine<<<dim3(24, 32), 256, 0, stream>>>(Opart, lpart, Yb);
  gemm_bt<1><<<dim3(8, 32), 256, 0, stream>>>(Yb, wprojT, b_proj, out,
                                              nullptr, nullptr, nullptr, 4096, 1024, 1024);
}

// Round 13
// 181.462 us; speedup vs baseline: 1.1059x; 1.1059x over previous
//
#include <hip/hip_runtime.h>

// CausalSelfAttention: B=2, T=2048, C=1024, H=16, HD=64.
// Inputs/outputs f32; internal bf16 MFMA.
//
// Pipeline (5 launches):
//   1. prep: fused {cast x -> xb bf16} + {transpose+cast w_attn} +
//      {transpose+cast w_proj} in one flat-grid kernel.
//   2. gemm_bt<QKV>: xb @ wattnT^T + b_attn -> Q,K bf16 [B,H,T,64]
//      (K pre-scaled by 0.125*log2e) and V DIRECTLY into fragment-
//      permuted Vt [bh][d][t]. Q/K blocks compute C^T via MFMA operand
//      swap -> u16x4 stores. XCD-swizzled block ids. BK=32, single-
//      buffered, 2 barriers/K-step — measured best (dbuf, BK=64,
//      read-XOR swizzle, counted-vmcnt all regressed: 54/65/50/56 vs 46).
//   3. attn_split: flash attention, S^T formulation, no-max softmax,
//      SPLIT-KV with balanced slice ranges; double-buffered XOR-swizzled
//      LDS tiles; one barrier per kv tile; raw v_exp_f32; setprio(1)
//      around MFMA cluster; (256,5) -> 5 blocks/CU.
//   4. attn_combine: sum <=4 partials, divide, write Y bf16
//   5. gemm_proj: Y @ wprojT^T + b_proj -> out f32. 128x64 tiles ->
//      512 blocks = 2 blocks/CU (the old 128x128 grid was 256 blocks =
//      1 block/CU, worst-case latency hiding).

typedef unsigned short u16;
typedef unsigned short u16x8 __attribute__((ext_vector_type(8)));
typedef unsigned short u16x4 __attribute__((ext_vector_type(4)));
typedef __bf16 bf16x8 __attribute__((ext_vector_type(8)));
typedef __bf16 bf16x4 __attribute__((ext_vector_type(4)));
typedef float f32x4 __attribute__((ext_vector_type(4)));

#define MFMA16(a, b, c) __builtin_amdgcn_mfma_f32_16x16x32_bf16(a, b, c, 0, 0, 0)

static __device__ __forceinline__ u16 f2b(float f) {
  union { float f; unsigned int i; } x; x.f = f;
  unsigned int r = x.i + 0x7fffu + ((x.i >> 16) & 1u);  // RNE
  return (u16)(r >> 16);
}
static __device__ __forceinline__ float b2f(u16 u) {
  union { unsigned int i; float f; } x; x.i = ((unsigned int)u) << 16; return x.f;
}

// async global->LDS, 16B per lane. LDS dest resolves to wave-uniform base
// (lane0's pointer) + lane*16 — our addressing is lane-linear so this matches.
static __device__ __forceinline__ void gload_lds16(const u16* g, u16* l) {
#if defined(__HIP_DEVICE_COMPILE__)
  __builtin_amdgcn_global_load_lds(
      (const __attribute__((address_space(1))) unsigned int*)g,
      (__attribute__((address_space(3))) unsigned int*)l,
      16, 0, 0);
#else
  (void)g; (void)l;
#endif
}

// ---------------------------------------------------------------- prep
// Fused: [0,2048) cast x f32->bf16 (8/thread); [2048,5120) transpose
// w_attn [1024][3072] -> wattnT [3072][1024]; [5120,6144) transpose
// w_proj [1024][1024] -> wprojT. Branch is block-uniform.
__global__ __launch_bounds__(256) void prep(
    const float* __restrict__ x, const float* __restrict__ w_attn,
    const float* __restrict__ w_proj, u16* __restrict__ xb,
    u16* __restrict__ wattnT, u16* __restrict__ wprojT) {
  __shared__ u16 tile[32][33];
  const int bid = blockIdx.x;
  const int tid = threadIdx.x;

  if (bid < 2048) {
    int i = (bid * 256 + tid) * 8;
    float4 a = *(const float4*)&x[i];
    float4 b = *(const float4*)&x[i + 4];
    u16x8 o;
    o[0] = f2b(a.x); o[1] = f2b(a.y); o[2] = f2b(a.z); o[3] = f2b(a.w);
    o[4] = f2b(b.x); o[5] = f2b(b.y); o[6] = f2b(b.z); o[7] = f2b(b.w);
    *(u16x8*)&xb[i] = o;
    return;
  }

  const float* in;
  u16* out;
  int bx, by, R, Cc;
  if (bid < 5120) {
    int b = bid - 2048;
    bx = b % 96; by = b / 96; R = 1024; Cc = 3072;
    in = w_attn; out = wattnT;
  } else {
    int b = bid - 5120;
    bx = b % 32; by = b / 32; R = 1024; Cc = 1024;
    in = w_proj; out = wprojT;
  }
  const int tx = tid & 31, ty = tid >> 5;  // 32 x 8
#pragma unroll
  for (int i = 0; i < 4; i++) {
    int r = by * 32 + ty + i * 8;
    int c = bx * 32 + tx;
    tile[ty + i * 8][tx] = f2b(in[r * Cc + c]);
  }
  __syncthreads();
#pragma unroll
  for (int i = 0; i < 4; i++) {
    int r = bx * 32 + ty + i * 8;
    int c = by * 32 + tx;
    out[r * R + c] = tile[tx][ty + i * 8];
  }
}

// ---------------------------------------------------------------- GEMM (QKV)
// BK=32, single-buffered, 2 barriers per K-step, 16KB LDS (measured best
// of every structure tried).
template <int MODE>
__global__ __launch_bounds__(256, 3) void gemm_bt(
    const u16* __restrict__ A, const u16* __restrict__ Bt,
    const float* __restrict__ bias, float* __restrict__ out,
    u16* __restrict__ Qb, u16* __restrict__ Kb, u16* __restrict__ Vtb,
    int M, int N, int K) {
  __shared__ u16 lA[128 * 32];
  __shared__ u16 lB[128 * 32];

  const int tid = threadIdx.x;
  const int lane = tid & 63;
  const int w = tid >> 6;
  const int wm = (w >> 1) * 64, wn = (w & 1) * 64;
  const int l15 = lane & 15, quad = lane >> 4;

  // XCD-aware swizzle: contiguous chunk of remapped ids per XCD.
  // nwg % 8 == 0 -> bijective.
  const int nx = gridDim.x;
  const int id = blockIdx.y * nx + blockIdx.x;
  const int chunk = (nx * gridDim.y) >> 3;
  const int nid = (id & 7) * chunk + (id >> 3);
  const int m0 = (nid / nx) * 128, n0 = (nid % nx) * 128;

  const bool swapcd = (MODE == 0) && (n0 < 2048);  // Q/K blocks: C^T

  const int srow = lane >> 2;
  const int scol = (lane & 3) * 8;

  f32x4 acc[4][4] = {};

  for (int k0 = 0; k0 < K; k0 += 32) {
    __syncthreads();
#pragma unroll
    for (int h = 0; h < 2; h++) {
      int r = h * 64 + w * 16 + srow;
      gload_lds16(&A[(m0 + r) * K + k0 + scol], &lA[h * 2048 + w * 512 + lane * 8]);
      gload_lds16(&Bt[(n0 + r) * K + k0 + scol], &lB[h * 2048 + w * 512 + lane * 8]);
    }
    __syncthreads();

    bf16x8 af[4], bfr[4];
#pragma unroll
    for (int mi = 0; mi < 4; mi++)
      af[mi] = *(const bf16x8*)&lA[(wm + mi * 16 + l15) * 32 + quad * 8];
#pragma unroll
    for (int ni = 0; ni < 4; ni++)
      bfr[ni] = *(const bf16x8*)&lB[(wn + ni * 16 + l15) * 32 + quad * 8];
    if (swapcd) {
#pragma unroll
      for (int mi = 0; mi < 4; mi++)
#pragma unroll
        for (int ni = 0; ni < 4; ni++)
          acc[mi][ni] = MFMA16(bfr[ni], af[mi], acc[mi][ni]);
    } else {
#pragma unroll
      for (int mi = 0; mi < 4; mi++)
#pragma unroll
        for (int ni = 0; ni < 4; ni++)
          acc[mi][ni] = MFMA16(af[mi], bfr[ni], acc[mi][ni]);
    }
  }

  if (MODE == 1) {
    // plain f32 out: acc[mi][ni][reg] is C[m][n], m=..+quad*4+reg, n=..+l15
#pragma unroll
    for (int mi = 0; mi < 4; mi++) {
#pragma unroll
      for (int ni = 0; ni < 4; ni++) {
        int n = n0 + wn + ni * 16 + l15;
        float bv = bias[n];
#pragma unroll
        for (int reg = 0; reg < 4; reg++) {
          int m = m0 + wm + mi * 16 + quad * 4 + reg;
          out[m * N + n] = acc[mi][ni][reg] + bv;
        }
      }
    }
  } else if (n0 < 2048) {
    // Q/K (swapped): lane holds n = n0+wn+ni*16+quad*4+reg, m = ..+l15.
    const int which = n0 >> 10;          // 0=q 1=k (uniform per block)
    u16* dst = which ? Kb : Qb;
    const float scale = which ? 0.18033688011112042f : 1.0f;  // 0.125*log2e
    const int b = m0 >> 11;
    const int hh = ((n0 & 1023) + wn) >> 6;
    const int tbase = (m0 & 2047) + wm + l15;
#pragma unroll
    for (int mi = 0; mi < 4; mi++) {
      u16* drow = dst + (((b << 4) + hh) * 2048 + tbase + mi * 16) * 64;
#pragma unroll
      for (int ni = 0; ni < 4; ni++) {
        int d0 = ni * 16 + quad * 4;
        float4 bv4 = *(const float4*)&bias[n0 + wn + d0];
        u16x4 o;
        o[0] = f2b((acc[mi][ni][0] + bv4.x) * scale);
        o[1] = f2b((acc[mi][ni][1] + bv4.y) * scale);
        o[2] = f2b((acc[mi][ni][2] + bv4.z) * scale);
        o[3] = f2b((acc[mi][ni][3] + bv4.w) * scale);
        *(u16x4*)&drow[d0] = o;
      }
    }
  } else {
    // V (unswapped): lane holds m = ..+quad*4+reg (4 consecutive t), fixed
    // d = ni*16+l15. Fragment permutation: tp = quad*8 + (mi&1)*4 + reg,
    // contiguous in reg -> u16x4 store into Vt[bh][d][t32 + tp].
    const int b = m0 >> 11;
    const int hh = ((n0 & 1023) + wn) >> 6;
    const int bh = (b << 4) + hh;
#pragma unroll
    for (int mi = 0; mi < 4; mi++) {
      int t32 = (m0 & 2047) + wm + (mi >> 1) * 32;
      int tp0 = quad * 8 + (mi & 1) * 4;
#pragma unroll
      for (int ni = 0; ni < 4; ni++) {
        int d = ni * 16 + l15;
        float bv = bias[n0 + wn + d];
        u16x4 o;
        o[0] = f2b(acc[mi][ni][0] + bv);
        o[1] = f2b(acc[mi][ni][1] + bv);
        o[2] = f2b(acc[mi][ni][2] + bv);
        o[3] = f2b(acc[mi][ni][3] + bv);
        *(u16x4*)&Vtb[(bh * 64 + d) * 2048 + t32 + tp0] = o;
      }
    }
  }
}

// ---------------------------------------------------------------- GEMM (proj)
// Y[4096x1024] @ wprojT^T[1024x1024] + b -> out f32. Tile 128x64 ->
// grid (16,32) = 512 blocks = 2 blocks/CU (vs 1 with 128x128 tiles).
// 4 waves as 2x2 over the tile; per-wave 64x32 output (acc[4][2]).
// Same BK=32 2-barrier loop; B-stage is a single gload per iter.
__global__ __launch_bounds__(256, 3) void gemm_proj(
    const u16* __restrict__ A, const u16* __restrict__ Bt,
    const float* __restrict__ bias, float* __restrict__ out) {
  __shared__ u16 lA[128 * 32];
  __shared__ u16 lB[64 * 32];

  const int tid = threadIdx.x;
  const int lane = tid & 63;
  const int w = tid >> 6;
  const int wm = (w >> 1) * 64, wn = (w & 1) * 32;
  const int l15 = lane & 15, quad = lane >> 4;

  // XCD swizzle (512 blocks, %8==0 -> bijective)
  const int nx = gridDim.x;                    // 16
  const int id = blockIdx.y * nx + blockIdx.x;
  const int chunk = (nx * gridDim.y) >> 3;     // 64
  const int nid = (id & 7) * chunk + (id >> 3);
  const int m0 = (nid / nx) * 128, n0 = (nid % nx) * 64;

  const int srow = lane >> 2;
  const int scol = (lane & 3) * 8;

  f32x4 acc[4][2] = {};

  for (int k0 = 0; k0 < 1024; k0 += 32) {
    __syncthreads();
#pragma unroll
    for (int h = 0; h < 2; h++) {
      int r = h * 64 + w * 16 + srow;
      gload_lds16(&A[(m0 + r) * 1024 + k0 + scol], &lA[h * 2048 + w * 512 + lane * 8]);
    }
    gload_lds16(&Bt[(n0 + w * 16 + srow) * 1024 + k0 + scol], &lB[w * 512 + lane * 8]);
    __syncthreads();

    bf16x8 af[4], bfr[2];
#pragma unroll
    for (int mi = 0; mi < 4; mi++)
      af[mi] = *(const bf16x8*)&lA[(wm + mi * 16 + l15) * 32 + quad * 8];
#pragma unroll
    for (int ni = 0; ni < 2; ni++)
      bfr[ni] = *(const bf16x8*)&lB[(wn + ni * 16 + l15) * 32 + quad * 8];
#pragma unroll
    for (int mi = 0; mi < 4; mi++)
#pragma unroll
      for (int ni = 0; ni < 2; ni++)
        acc[mi][ni] = MFMA16(af[mi], bfr[ni], acc[mi][ni]);
  }

#pragma unroll
  for (int mi = 0; mi < 4; mi++) {
#pragma unroll
    for (int ni = 0; ni < 2; ni++) {
      int n = n0 + wn + ni * 16 + l15;
      float bv = bias[n];
#pragma unroll
      for (int reg = 0; reg < 4; reg++) {
        int m = m0 + wm + mi * 16 + quad * 4 + reg;
        out[m * 1024 + n] = acc[mi][ni][reg] + bv;
      }
    }
  }
}

// ---------------------------------------------------------------- attention
// Split-kv flash attention. Block = (x -> (qt, slice), bh). 4 waves x 16
// q-rows. Slice s of ns covers kv tiles [s*(qt+1)/ns, (s+1)*(qt+1)/ns).
// S^T formulation; l via ones-B MFMA. Double-buffered LDS, one barrier
// per tile. LDS tiles XOR-swizzled: row stride 64 u16 (128B), 16B chunk
// ^= (row&7) -> conflict-free b128 reads. setprio(1) around MFMA cluster.
__global__ __launch_bounds__(256, 5) void attn_split(
    const u16* __restrict__ Qg, const u16* __restrict__ Kg,
    const u16* __restrict__ Vt, u16* __restrict__ Yg,
    u16* __restrict__ Opart, float* __restrict__ lpart) {
  __shared__ u16 lk[2][64 * 64];     // K tile  [kv][d]  (swizzled)
  __shared__ u16 lvt[2][64 * 64];    // Vt tile [d][kv]  (swizzled, frag order)

  const int x = blockIdx.x;
  const int bh = blockIdx.y;
  int qt, s, ns;
  if (x < 8)       { qt = x;                s = 0;            ns = 1; }
  else if (x < 24) { int r = x - 8;  qt = 8  + (r >> 1); s = r & 1; ns = 2; }
  else if (x < 48) { int r = x - 24; qt = 16 + r / 3;    s = r % 3; ns = 3; }
  else             { int r = x - 48; qt = 24 + (r >> 2); s = r & 3; ns = 4; }
  const int total = qt + 1;
  const int kts  = (s * total) / ns;
  const int kend = ((s + 1) * total) / ns;

  const int tid = threadIdx.x;
  const int lane = tid & 63;
  const int w = tid >> 6;
  const int l15 = lane & 15, quad = lane >> 4;
  const int qbase = qt * 64;
  const int base = bh * 2048 * 64;
  const int vbase = bh * 64 * 2048;
  const int qloc = w * 16 + l15;
  const int xsw = (l15 & 7) << 3;    // read-side swizzle (row&7 == l15&7)

  const int sr = tid >> 3;           // 0..31
  const int sc = (tid & 7) * 8;      // 0..56

  // Q B-fragments
  const u16* qrow = Qg + base + (qbase + w * 16 + l15) * 64;
  bf16x8 bq0 = *(const bf16x8*)&qrow[quad * 8];
  bf16x8 bq1 = *(const bf16x8*)&qrow[32 + quad * 8];

  u16x8 onesu = {0x3F80, 0x3F80, 0x3F80, 0x3F80, 0x3F80, 0x3F80, 0x3F80, 0x3F80};
  bf16x8 ones = *(const bf16x8*)&onesu;

  const u16* kp = Kg + base;
  const u16* vp = Vt + vbase;

  // preload first tile of the slice
  u16x8 kr[2], vr[2];
  {
    int kvb = kts * 64;
#pragma unroll
    for (int h = 0; h < 2; h++) {
      int r = sr + h * 32;
      kr[h] = *(const u16x8*)&kp[(kvb + r) * 64 + sc];
      vr[h] = *(const u16x8*)&vp[r * 2048 + kvb + sc];
    }
  }

  f32x4 oacc[4] = {};
  f32x4 lacc = {};

  int cur = 0;
  for (int kt = kts; kt < kend; kt++) {
    u16* lkc = lk[cur];
    u16* lvc = lvt[cur];
#pragma unroll
    for (int h = 0; h < 2; h++) {
      int r = sr + h * 32;
      int cs = sc ^ ((r & 7) << 3);          // swizzled 16B chunk
      *(u16x8*)&lkc[r * 64 + cs] = kr[h];
      *(u16x8*)&lvc[r * 64 + cs] = vr[h];
    }
    __syncthreads();
    if (kt + 1 < kend) {
      int kvb = (kt + 1) * 64;
#pragma unroll
      for (int h = 0; h < 2; h++) {
        int r = sr + h * 32;
        kr[h] = *(const u16x8*)&kp[(kvb + r) * 64 + sc];
        vr[h] = *(const u16x8*)&vp[r * 2048 + kvb + sc];
      }
    }

    const bool diag = (kt == qt);

#pragma unroll
    for (int u = 0; u < 2; u++) {
      bf16x8 pa;
      __builtin_amdgcn_s_setprio(1);
#pragma unroll
      for (int half = 0; half < 2; half++) {
        int nt = 2 * u + half;
        const u16* kb = &lkc[(nt * 16 + l15) * 64];
        bf16x8 ak0 = *(const bf16x8*)&kb[(quad * 8) ^ xsw];
        bf16x8 ak1 = *(const bf16x8*)&kb[(32 + quad * 8) ^ xsw];
        f32x4 st = {};
        st = MFMA16(ak0, bq0, st);
        st = MFMA16(ak1, bq1, st);
#pragma unroll
        for (int reg = 0; reg < 4; reg++) {
          float sv = st[reg];
          if (diag && (nt * 16 + quad * 4 + reg) > qloc) sv = -1e30f;
          pa[half * 4 + reg] = (__bf16)__builtin_amdgcn_exp2f(sv);
        }
      }
      // row-sum on the MFMA pipe: lacc[reg] = l[q = w*16 + quad*4 + reg]
      lacc = MFMA16(pa, ones, lacc);
#pragma unroll
      for (int dt = 0; dt < 4; dt++) {
        bf16x8 bv = *(const bf16x8*)&lvc[(dt * 16 + l15) * 64 +
                                         ((u * 32 + quad * 8) ^ xsw)];
        oacc[dt] = MFMA16(pa, bv, oacc[dt]);
      }
      __builtin_amdgcn_s_setprio(0);
    }
    cur ^= 1;
  }

  if (ns == 1) {
    const int b = bh >> 4, hh = bh & 15;
    float inv[4];
#pragma unroll
    for (int reg = 0; reg < 4; reg++) inv[reg] = 1.0f / lacc[reg];
#pragma unroll
    for (int dt = 0; dt < 4; dt++)
#pragma unroll
      for (int reg = 0; reg < 4; reg++) {
        int q = qbase + w * 16 + quad * 4 + reg;
        int col = hh * 64 + dt * 16 + l15;
        Yg[(b * 2048 + q) * 1024 + col] = f2b(oacc[dt][reg] * inv[reg]);
      }
  } else {
    const int p = bh * 80 + x;
    u16* op = Opart + p * 4096 + (w * 16) * 64;  // rows w*16..w*16+15
#pragma unroll
    for (int dt = 0; dt < 4; dt++)
#pragma unroll
      for (int reg = 0; reg < 4; reg++)
        op[(quad * 4 + reg) * 64 + dt * 16 + l15] = f2b(oacc[dt][reg]);
    if (l15 == 0) {
#pragma unroll
      for (int reg = 0; reg < 4; reg++)
        lpart[p * 64 + w * 16 + quad * 4 + reg] = lacc[reg];
    }
  }
}

// combine <=4 partials for qt >= 8
__global__ __launch_bounds__(256) void attn_combine(
    const u16* __restrict__ Opart, const float* __restrict__ lpart,
    u16* __restrict__ Yg) {
  const int qt = 8 + blockIdx.x;    // 8..31
  const int bh = blockIdx.y;
  const int tid = threadIdx.x;
  const int row = tid >> 2;         // 0..63
  const int cg = (tid & 3) * 16;    // 0,16,32,48
  int xb, ns;
  if (qt < 16)      { xb = 8  + (qt - 8) * 2;  ns = 2; }
  else if (qt < 24) { xb = 24 + (qt - 16) * 3; ns = 3; }
  else              { xb = 48 + (qt - 24) * 4; ns = 4; }

  float acc[16] = {};
  float lsum = 0.f;
  for (int i = 0; i < ns; i++) {
    int p = bh * 80 + xb + i;
    lsum += lpart[p * 64 + row];
    const u16* oprow = Opart + p * 4096 + row * 64 + cg;
    u16x8 a = *(const u16x8*)&oprow[0];
    u16x8 b = *(const u16x8*)&oprow[8];
#pragma unroll
    for (int j = 0; j < 8; j++) { acc[j] += b2f(a[j]); acc[8 + j] += b2f(b[j]); }
  }
  float inv = 1.0f / lsum;
  u16x8 o0, o1;
#pragma unroll
  for (int j = 0; j < 8; j++) { o0[j] = f2b(acc[j] * inv); o1[j] = f2b(acc[8 + j] * inv); }
  const int b = bh >> 4, hh = bh & 15;
  u16* y = Yg + ((long)(b * 2048 + qt * 64 + row)) * 1024 + hh * 64 + cg;
  *(u16x8*)&y[0] = o0;
  *(u16x8*)&y[8] = o1;
}

// ---------------------------------------------------------------- launch
extern "C" void kernel_launch(void* const* d_in, const int* in_sizes, int n_in,
                              void* d_out, int out_size, void* d_ws, size_t ws_size,
                              hipStream_t stream) {
  const float* x      = (const float*)d_in[0];
  const float* w_attn = (const float*)d_in[1];
  const float* b_attn = (const float*)d_in[2];
  const float* w_proj = (const float*)d_in[3];
  const float* b_proj = (const float*)d_in[4];
  float* out = (float*)d_out;

  char* ws = (char*)d_ws;
  u16* wattnT = (u16*)(ws);                  //  6291456 B
  u16* wprojT = (u16*)(ws + 6291456);        //  2097152 B
  u16* xb     = (u16*)(ws + 8388608);        //  8388608 B
  u16* Qb     = (u16*)(ws + 16777216);
  u16* Kb     = (u16*)(ws + 25165824);
  u16* Vt     = (u16*)(ws + 33554432);       //  written directly by QKV gemm
  u16* Yb     = (u16*)(ws + 41943040);       //  8388608 B -> 50331648
  u16* Opart  = (u16*)(ws + 50331648);       //  20971520 B
  float* lpart = (float*)(ws + 71303168);    //  655360 B -> 71958528 total

  prep<<<6144, 256, 0, stream>>>(x, w_attn, w_proj, xb, wattnT, wprojT);
  gemm_bt<0><<<dim3(24, 32), 256, 0, stream>>>(xb, wattnT, b_attn, nullptr,
                                               Qb, Kb, Vt, 4096, 3072, 1024);
  attn_split<<<dim3(80, 32), 256, 0, stream>>>(Qb, Kb, Vt, Yb, Opart, lpart);
  attn_combine<<<dim3(24, 32), 256, 0, stream>>>(Opart, lpart, Yb);
  gemm_proj<<<dim3(16, 32), 256, 0, stream>>>(Yb, wprojT, b_proj, out);
}